// Round 1
// baseline (2982.136 us; speedup 1.0000x reference)
//
#include <hip/hip_runtime.h>

#define D 128
#define NN 100000
#define NE 1600000
#define TILE_R 32

// ---------------------------------------------------------------------------
// K1: scatter-add  neigh[dst] += h[src]   (32 lanes per edge, float4 per lane)
// ---------------------------------------------------------------------------
__global__ __launch_bounds__(256) void scatter_add_kernel(
    const float* __restrict__ h, const int* __restrict__ src,
    const int* __restrict__ dst, float* __restrict__ neigh)
{
    int gid  = blockIdx.x * 256 + threadIdx.x;
    int edge = gid >> 5;
    int lane = gid & 31;
    if (edge >= NE) return;
    int s = src[edge];
    int d = dst[edge];
    float4 v = ((const float4*)(h + (size_t)s * D))[lane];
    float* o = neigh + (size_t)d * D + (size_t)lane * 4;
    unsafeAtomicAdd(o + 0, v.x);
    unsafeAtomicAdd(o + 1, v.y);
    unsafeAtomicAdd(o + 2, v.z);
    unsafeAtomicAdd(o + 3, v.w);
}

// ---------------------------------------------------------------------------
// K2/K3: fused MLP GEMM.  MODE 1: x=(1+eps)*h+xin, out=relu(x@W+b)  (in-place)
//        MODE 2: out=(xin@W+b)*snorm                               (in-place)
// 256 thr, 32 rows/block; LDS = W(64KB) + xtile(16KB) = 80KB -> 2 blocks/CU.
// Thread micro-tile: 2 rows x 8 cols.
// ---------------------------------------------------------------------------
template <int MODE>
__global__ __launch_bounds__(256) void mlp_gemm_kernel(
    const float* __restrict__ xin, const float* __restrict__ h,
    const float* __restrict__ epsp, const float* __restrict__ W,
    const float* __restrict__ bias, const float* __restrict__ snorm,
    float* __restrict__ out)
{
    __shared__ float w_lds[D][D];      // 64 KB
    __shared__ float xs[TILE_R][D];    // 16 KB
    const int tid = threadIdx.x;

    // stage W: 4096 float4 / 256 threads = 16 each, coalesced
    {
        const float4* Wv = (const float4*)W;
        float4* wv = (float4*)w_lds;
#pragma unroll
        for (int i = 0; i < (D * D / 4) / 256; ++i)
            wv[tid + i * 256] = Wv[tid + i * 256];
    }
    const int row0 = blockIdx.x * TILE_R;
    {
        const float4* Av = (const float4*)(xin + (size_t)row0 * D);
        float4* xv = (float4*)xs;
        if (MODE == 1) {
            const float sc = 1.0f + epsp[0];
            const float4* Hv = (const float4*)(h + (size_t)row0 * D);
#pragma unroll
            for (int i = 0; i < (TILE_R * D / 4) / 256; ++i) {
                float4 a  = Av[tid + i * 256];
                float4 hv = Hv[tid + i * 256];
                a.x = fmaf(sc, hv.x, a.x);
                a.y = fmaf(sc, hv.y, a.y);
                a.z = fmaf(sc, hv.z, a.z);
                a.w = fmaf(sc, hv.w, a.w);
                xv[tid + i * 256] = a;
            }
        } else {
#pragma unroll
            for (int i = 0; i < (TILE_R * D / 4) / 256; ++i)
                xv[tid + i * 256] = Av[tid + i * 256];
        }
    }
    __syncthreads();

    const int cg = tid & 15;   // col-group: 8 cols
    const int rg = tid >> 4;   // row-group: 2 rows
    const int c0 = cg * 8;
    const int r0 = rg * 2;

    float acc[2][8];
#pragma unroll
    for (int i = 0; i < 2; ++i)
#pragma unroll
        for (int j = 0; j < 8; ++j) acc[i][j] = 0.0f;

#pragma unroll 4
    for (int k0 = 0; k0 < D; k0 += 4) {
        float4 xa = *(const float4*)&xs[r0][k0];
        float4 xb = *(const float4*)&xs[r0 + 1][k0];
        float xav[4] = {xa.x, xa.y, xa.z, xa.w};
        float xbv[4] = {xb.x, xb.y, xb.z, xb.w};
#pragma unroll
        for (int kk = 0; kk < 4; ++kk) {
            float4 w0 = *(const float4*)&w_lds[k0 + kk][c0];
            float4 w1 = *(const float4*)&w_lds[k0 + kk][c0 + 4];
            float wv[8] = {w0.x, w0.y, w0.z, w0.w, w1.x, w1.y, w1.z, w1.w};
            float va = xav[kk], vb = xbv[kk];
#pragma unroll
            for (int j = 0; j < 8; ++j) {
                acc[0][j] = fmaf(va, wv[j], acc[0][j]);
                acc[1][j] = fmaf(vb, wv[j], acc[1][j]);
            }
        }
    }

    float bv[8];
    *(float4*)&bv[0] = *(const float4*)&bias[c0];
    *(float4*)&bv[4] = *(const float4*)&bias[c0 + 4];
#pragma unroll
    for (int i = 0; i < 2; ++i) {
        const int row = row0 + r0 + i;
        float o[8];
        if (MODE == 1) {
#pragma unroll
            for (int j = 0; j < 8; ++j) o[j] = fmaxf(acc[i][j] + bv[j], 0.0f);
        } else {
            const float sn = snorm[row];
#pragma unroll
            for (int j = 0; j < 8; ++j) o[j] = (acc[i][j] + bv[j]) * sn;
        }
        float4* op = (float4*)(out + (size_t)row * D + c0);
        op[0] = *(float4*)&o[0];
        op[1] = *(float4*)&o[4];
    }
}

// ---------------------------------------------------------------------------
// K4: per-column sum & sumsq over all rows  (block partials -> double atomics)
// ---------------------------------------------------------------------------
__global__ __launch_bounds__(256) void bn_stats_kernel(
    const float* __restrict__ y, double* __restrict__ stats)
{
    __shared__ float ssum[D], ssq[D];
    const int tid = threadIdx.x;
    if (tid < D) { ssum[tid] = 0.0f; ssq[tid] = 0.0f; }
    __syncthreads();
    const int rw = tid >> 5;       // 0..7
    const int cf = tid & 31;       // float4 column index
    const int r0 = blockIdx.x * 256;
    const int rend = (r0 + 256 < NN) ? r0 + 256 : NN;
    float s0 = 0, s1 = 0, s2 = 0, s3 = 0, q0 = 0, q1 = 0, q2 = 0, q3 = 0;
    for (int r = r0 + rw; r < rend; r += 8) {
        float4 v = *(const float4*)&y[(size_t)r * D + (size_t)cf * 4];
        s0 += v.x; s1 += v.y; s2 += v.z; s3 += v.w;
        q0 += v.x * v.x; q1 += v.y * v.y; q2 += v.z * v.z; q3 += v.w * v.w;
    }
    atomicAdd(&ssum[cf * 4 + 0], s0);
    atomicAdd(&ssum[cf * 4 + 1], s1);
    atomicAdd(&ssum[cf * 4 + 2], s2);
    atomicAdd(&ssum[cf * 4 + 3], s3);
    atomicAdd(&ssq[cf * 4 + 0], q0);
    atomicAdd(&ssq[cf * 4 + 1], q1);
    atomicAdd(&ssq[cf * 4 + 2], q2);
    atomicAdd(&ssq[cf * 4 + 3], q3);
    __syncthreads();
    if (tid < D) {
        atomicAdd(&stats[tid], (double)ssum[tid]);
        atomicAdd(&stats[D + tid], (double)ssq[tid]);
    }
}

// ---------------------------------------------------------------------------
// K5: fold stats into per-column scale/shift
// ---------------------------------------------------------------------------
__global__ void bn_prep_kernel(const double* __restrict__ stats,
                               const float* __restrict__ gamma,
                               const float* __restrict__ beta,
                               float* __restrict__ sc_sh)
{
    int c = threadIdx.x;  // 128 threads
    double mean = stats[c] * (1.0 / NN);
    double var  = stats[D + c] * (1.0 / NN) - mean * mean;
    float rs = rsqrtf((float)var + 1e-5f);
    float sc = gamma[c] * rs;
    sc_sh[c]     = sc;
    sc_sh[D + c] = beta[c] - (float)mean * sc;
}

// ---------------------------------------------------------------------------
// K6: out = h + relu(y*sc + sh)
// ---------------------------------------------------------------------------
__global__ __launch_bounds__(256) void finalize_kernel(
    const float* __restrict__ y, const float* __restrict__ h,
    const float* __restrict__ sc_sh, float* __restrict__ out)
{
    int i  = blockIdx.x * 256 + threadIdx.x;   // float4 index, N*32 total (exact)
    int cf = i & 31;
    float4 yv = ((const float4*)y)[i];
    float4 hv = ((const float4*)h)[i];
    float4 sc = ((const float4*)sc_sh)[cf];
    float4 sh = ((const float4*)(sc_sh + D))[cf];
    float4 o;
    o.x = hv.x + fmaxf(fmaf(yv.x, sc.x, sh.x), 0.0f);
    o.y = hv.y + fmaxf(fmaf(yv.y, sc.y, sh.y), 0.0f);
    o.z = hv.z + fmaxf(fmaf(yv.z, sc.z, sh.z), 0.0f);
    o.w = hv.w + fmaxf(fmaf(yv.w, sc.w, sh.w), 0.0f);
    ((float4*)out)[i] = o;
}

// ---------------------------------------------------------------------------
extern "C" void kernel_launch(void* const* d_in, const int* in_sizes, int n_in,
                              void* d_out, int out_size, void* d_ws, size_t ws_size,
                              hipStream_t stream)
{
    const float* h     = (const float*)d_in[0];
    const float* snorm = (const float*)d_in[1];
    const float* eps   = (const float*)d_in[2];
    const float* W1    = (const float*)d_in[3];
    const float* b1    = (const float*)d_in[4];
    const float* W2    = (const float*)d_in[5];
    const float* b2    = (const float*)d_in[6];
    const float* gamma = (const float*)d_in[7];
    const float* beta  = (const float*)d_in[8];
    const int*   src   = (const int*)d_in[9];
    const int*   dst   = (const int*)d_in[10];
    float* out = (float*)d_out;

    const size_t BUF_BYTES = (size_t)NN * D * sizeof(float);       // 51.2 MB
    float*  buf   = (float*)d_ws;                                  // neigh -> hidden -> y (in-place)
    double* stats = (double*)((char*)d_ws + BUF_BYTES);            // 256 doubles
    float*  sc_sh = (float*)((char*)d_ws + BUF_BYTES + 2048);      // 256 floats

    // zero neigh accumulator + stats
    hipMemsetAsync(d_ws, 0, BUF_BYTES + 2048, stream);

    // message passing: neigh[dst] += h[src]
    scatter_add_kernel<<<NE * 32 / 256, 256, 0, stream>>>(h, src, dst, buf);

    // hidden = relu(((1+eps)h + neigh) @ W1 + b1)      (in-place on buf)
    mlp_gemm_kernel<1><<<NN / TILE_R, 256, 0, stream>>>(buf, h, eps, W1, b1, nullptr, buf);
    // y = (hidden @ W2 + b2) * snorm                   (in-place on buf)
    mlp_gemm_kernel<2><<<NN / TILE_R, 256, 0, stream>>>(buf, nullptr, nullptr, W2, b2, snorm, buf);

    // batch-norm statistics
    bn_stats_kernel<<<(NN + 255) / 256, 256, 0, stream>>>(buf, stats);
    bn_prep_kernel<<<1, D, 0, stream>>>(stats, gamma, beta, sc_sh);

    // out = h + relu(bn(y))
    finalize_kernel<<<NN * D / 4 / 256, 256, 0, stream>>>(buf, h, sc_sh, out);
}

// Round 2
// 600.512 us; speedup vs baseline: 4.9660x; 4.9660x over previous
//
#include <hip/hip_runtime.h>

#define D 128
#define NN 100000
#define NE 1600000
#define TILE_R 32
#define SCAN_NBLK 98   // ceil(NN / 1024)

// ---------------------------------------------------------------------------
// CSR build K1: per-dst degree count
// ---------------------------------------------------------------------------
__global__ __launch_bounds__(256) void count_kernel(
    const int* __restrict__ dst, int* __restrict__ cnt)
{
    int e = blockIdx.x * 256 + threadIdx.x;
    if (e < NE) atomicAdd(&cnt[dst[e]], 1);
}

// ---------------------------------------------------------------------------
// CSR build K2: per-block exclusive scan (1024 elements / block)
// ---------------------------------------------------------------------------
__global__ __launch_bounds__(256) void scan_local_kernel(
    const int* __restrict__ cnt, int* __restrict__ pre, int* __restrict__ blkSum)
{
    __shared__ int lds[256];
    const int t = threadIdx.x;
    const int base = blockIdx.x * 1024 + t * 4;
    int4 v = {0, 0, 0, 0};
    if (base + 3 < NN) v = *(const int4*)&cnt[base];
    else {
        if (base + 0 < NN) v.x = cnt[base + 0];
        if (base + 1 < NN) v.y = cnt[base + 1];
        if (base + 2 < NN) v.z = cnt[base + 2];
        if (base + 3 < NN) v.w = cnt[base + 3];
    }
    const int s = v.x + v.y + v.z + v.w;
    lds[t] = s;
    __syncthreads();
    for (int off = 1; off < 256; off <<= 1) {
        int val = 0;
        if (t >= off) val = lds[t - off];
        __syncthreads();
        if (t >= off) lds[t] += val;
        __syncthreads();
    }
    const int excl = lds[t] - s;
    if (t == 255) blkSum[blockIdx.x] = lds[255];
    int4 o;
    o.x = excl;
    o.y = excl + v.x;
    o.z = excl + v.x + v.y;
    o.w = excl + v.x + v.y + v.z;
    if (base + 3 < NN) *(int4*)&pre[base] = o;
    else {
        if (base + 0 < NN) pre[base + 0] = o.x;
        if (base + 1 < NN) pre[base + 1] = o.y;
        if (base + 2 < NN) pre[base + 2] = o.z;
        if (base + 3 < NN) pre[base + 3] = o.w;
    }
}

// ---------------------------------------------------------------------------
// CSR build K3: scan the 98 block sums (single block)
// ---------------------------------------------------------------------------
__global__ __launch_bounds__(128) void scan_blk_kernel(
    const int* __restrict__ blkSum, int* __restrict__ blkOfs)
{
    __shared__ int lds[128];
    const int t = threadIdx.x;
    int s = (t < SCAN_NBLK) ? blkSum[t] : 0;
    lds[t] = s;
    __syncthreads();
    for (int off = 1; off < 128; off <<= 1) {
        int val = 0;
        if (t >= off) val = lds[t - off];
        __syncthreads();
        if (t >= off) lds[t] += val;
        __syncthreads();
    }
    blkOfs[t] = lds[t] - s;
}

// ---------------------------------------------------------------------------
// CSR build K4: row_start[n] = pre[n] + blkOfs[n/1024]; cursor = copy
// ---------------------------------------------------------------------------
__global__ __launch_bounds__(256) void scan_finish_kernel(
    const int* __restrict__ pre, const int* __restrict__ blkOfs,
    int* __restrict__ row_start, int* __restrict__ cursor)
{
    int n = blockIdx.x * 256 + threadIdx.x;
    if (n > NN) return;
    int v = (n == NN) ? NE : pre[n] + blkOfs[n >> 10];
    row_start[n] = v;
    if (n < NN) cursor[n] = v;
}

// ---------------------------------------------------------------------------
// CSR build K5: bucket the src ids by dst
// ---------------------------------------------------------------------------
__global__ __launch_bounds__(256) void fill_kernel(
    const int* __restrict__ src, const int* __restrict__ dst,
    int* __restrict__ cursor, int* __restrict__ eidx)
{
    int e = blockIdx.x * 256 + threadIdx.x;
    if (e >= NE) return;
    int pos = atomicAdd(&cursor[dst[e]], 1);
    eidx[pos] = src[e];
}

// ---------------------------------------------------------------------------
// K6: gather  x[n] = (1+eps)*h[n] + sum_{e in csr(n)} h[eidx[e]]
//     32 lanes per node, float4 per lane
// ---------------------------------------------------------------------------
__global__ __launch_bounds__(256) void gather_kernel(
    const float* __restrict__ h, const int* __restrict__ row_start,
    const int* __restrict__ eidx, const float* __restrict__ epsp,
    float* __restrict__ x)
{
    int gid  = blockIdx.x * 256 + threadIdx.x;
    int node = gid >> 5;
    int lane = gid & 31;
    if (node >= NN) return;
    const int s0 = row_start[node];
    const int s1 = row_start[node + 1];
    const float sc = 1.0f + epsp[0];
    float4 hv = ((const float4*)(h + (size_t)node * D))[lane];
    float ax = sc * hv.x, ay = sc * hv.y, az = sc * hv.z, aw = sc * hv.w;
    for (int e = s0; e < s1; ++e) {
        int s = eidx[e];
        float4 v = ((const float4*)(h + (size_t)s * D))[lane];
        ax += v.x; ay += v.y; az += v.z; aw += v.w;
    }
    float4 o = {ax, ay, az, aw};
    ((float4*)(x + (size_t)node * D))[lane] = o;
}

// ---------------------------------------------------------------------------
// K7/K8: MLP GEMM.  MODE 1: out=relu(xin@W+b)   MODE 2: out=(xin@W+b)*snorm
// 256 thr, 32 rows/block; LDS = W(64KB) + xtile(16KB) = 80KB -> 2 blocks/CU.
// ---------------------------------------------------------------------------
template <int MODE>
__global__ __launch_bounds__(256) void mlp_gemm_kernel(
    const float* __restrict__ xin, const float* __restrict__ W,
    const float* __restrict__ bias, const float* __restrict__ snorm,
    float* __restrict__ out)
{
    __shared__ float w_lds[D][D];      // 64 KB
    __shared__ float xs[TILE_R][D];    // 16 KB
    const int tid = threadIdx.x;

    {
        const float4* Wv = (const float4*)W;
        float4* wv = (float4*)w_lds;
#pragma unroll
        for (int i = 0; i < (D * D / 4) / 256; ++i)
            wv[tid + i * 256] = Wv[tid + i * 256];
    }
    const int row0 = blockIdx.x * TILE_R;
    {
        const float4* Av = (const float4*)(xin + (size_t)row0 * D);
        float4* xv = (float4*)xs;
#pragma unroll
        for (int i = 0; i < (TILE_R * D / 4) / 256; ++i)
            xv[tid + i * 256] = Av[tid + i * 256];
    }
    __syncthreads();

    const int cg = tid & 15;
    const int rg = tid >> 4;
    const int c0 = cg * 8;
    const int r0 = rg * 2;

    float acc[2][8];
#pragma unroll
    for (int i = 0; i < 2; ++i)
#pragma unroll
        for (int j = 0; j < 8; ++j) acc[i][j] = 0.0f;

#pragma unroll 4
    for (int k0 = 0; k0 < D; k0 += 4) {
        float4 xa = *(const float4*)&xs[r0][k0];
        float4 xb = *(const float4*)&xs[r0 + 1][k0];
        float xav[4] = {xa.x, xa.y, xa.z, xa.w};
        float xbv[4] = {xb.x, xb.y, xb.z, xb.w};
#pragma unroll
        for (int kk = 0; kk < 4; ++kk) {
            float4 w0 = *(const float4*)&w_lds[k0 + kk][c0];
            float4 w1 = *(const float4*)&w_lds[k0 + kk][c0 + 4];
            float wv[8] = {w0.x, w0.y, w0.z, w0.w, w1.x, w1.y, w1.z, w1.w};
            float va = xav[kk], vb = xbv[kk];
#pragma unroll
            for (int j = 0; j < 8; ++j) {
                acc[0][j] = fmaf(va, wv[j], acc[0][j]);
                acc[1][j] = fmaf(vb, wv[j], acc[1][j]);
            }
        }
    }

    float bv[8];
    *(float4*)&bv[0] = *(const float4*)&bias[c0];
    *(float4*)&bv[4] = *(const float4*)&bias[c0 + 4];
#pragma unroll
    for (int i = 0; i < 2; ++i) {
        const int row = row0 + r0 + i;
        float o[8];
        if (MODE == 1) {
#pragma unroll
            for (int j = 0; j < 8; ++j) o[j] = fmaxf(acc[i][j] + bv[j], 0.0f);
        } else {
            const float sn = snorm[row];
#pragma unroll
            for (int j = 0; j < 8; ++j) o[j] = (acc[i][j] + bv[j]) * sn;
        }
        float4* op = (float4*)(out + (size_t)row * D + c0);
        op[0] = *(float4*)&o[0];
        op[1] = *(float4*)&o[4];
    }
}

// ---------------------------------------------------------------------------
// K9: per-column sum & sumsq (block partials -> double atomics)
// ---------------------------------------------------------------------------
__global__ __launch_bounds__(256) void bn_stats_kernel(
    const float* __restrict__ y, double* __restrict__ stats)
{
    __shared__ float ssum[D], ssq[D];
    const int tid = threadIdx.x;
    if (tid < D) { ssum[tid] = 0.0f; ssq[tid] = 0.0f; }
    __syncthreads();
    const int rw = tid >> 5;
    const int cf = tid & 31;
    const int r0 = blockIdx.x * 256;
    const int rend = (r0 + 256 < NN) ? r0 + 256 : NN;
    float s0 = 0, s1 = 0, s2 = 0, s3 = 0, q0 = 0, q1 = 0, q2 = 0, q3 = 0;
    for (int r = r0 + rw; r < rend; r += 8) {
        float4 v = *(const float4*)&y[(size_t)r * D + (size_t)cf * 4];
        s0 += v.x; s1 += v.y; s2 += v.z; s3 += v.w;
        q0 += v.x * v.x; q1 += v.y * v.y; q2 += v.z * v.z; q3 += v.w * v.w;
    }
    atomicAdd(&ssum[cf * 4 + 0], s0);
    atomicAdd(&ssum[cf * 4 + 1], s1);
    atomicAdd(&ssum[cf * 4 + 2], s2);
    atomicAdd(&ssum[cf * 4 + 3], s3);
    atomicAdd(&ssq[cf * 4 + 0], q0);
    atomicAdd(&ssq[cf * 4 + 1], q1);
    atomicAdd(&ssq[cf * 4 + 2], q2);
    atomicAdd(&ssq[cf * 4 + 3], q3);
    __syncthreads();
    if (tid < D) {
        atomicAdd(&stats[tid], (double)ssum[tid]);
        atomicAdd(&stats[D + tid], (double)ssq[tid]);
    }
}

// ---------------------------------------------------------------------------
// K10: fold stats into per-column scale/shift
// ---------------------------------------------------------------------------
__global__ void bn_prep_kernel(const double* __restrict__ stats,
                               const float* __restrict__ gamma,
                               const float* __restrict__ beta,
                               float* __restrict__ sc_sh)
{
    int c = threadIdx.x;
    double mean = stats[c] * (1.0 / NN);
    double var  = stats[D + c] * (1.0 / NN) - mean * mean;
    float rs = rsqrtf((float)var + 1e-5f);
    float sc = gamma[c] * rs;
    sc_sh[c]     = sc;
    sc_sh[D + c] = beta[c] - (float)mean * sc;
}

// ---------------------------------------------------------------------------
// K11: out = h + relu(y*sc + sh)
// ---------------------------------------------------------------------------
__global__ __launch_bounds__(256) void finalize_kernel(
    const float* __restrict__ y, const float* __restrict__ h,
    const float* __restrict__ sc_sh, float* __restrict__ out)
{
    int i  = blockIdx.x * 256 + threadIdx.x;
    int cf = i & 31;
    float4 yv = ((const float4*)y)[i];
    float4 hv = ((const float4*)h)[i];
    float4 sc = ((const float4*)sc_sh)[cf];
    float4 sh = ((const float4*)(sc_sh + D))[cf];
    float4 o;
    o.x = hv.x + fmaxf(fmaf(yv.x, sc.x, sh.x), 0.0f);
    o.y = hv.y + fmaxf(fmaf(yv.y, sc.y, sh.y), 0.0f);
    o.z = hv.z + fmaxf(fmaf(yv.z, sc.z, sh.z), 0.0f);
    o.w = hv.w + fmaxf(fmaf(yv.w, sc.w, sh.w), 0.0f);
    ((float4*)out)[i] = o;
}

// ---------------------------------------------------------------------------
extern "C" void kernel_launch(void* const* d_in, const int* in_sizes, int n_in,
                              void* d_out, int out_size, void* d_ws, size_t ws_size,
                              hipStream_t stream)
{
    const float* h     = (const float*)d_in[0];
    const float* snorm = (const float*)d_in[1];
    const float* eps   = (const float*)d_in[2];
    const float* W1    = (const float*)d_in[3];
    const float* b1    = (const float*)d_in[4];
    const float* W2    = (const float*)d_in[5];
    const float* b2    = (const float*)d_in[6];
    const float* gamma = (const float*)d_in[7];
    const float* beta  = (const float*)d_in[8];
    const int*   src   = (const int*)d_in[9];
    const int*   dst   = (const int*)d_in[10];
    float* out = (float*)d_out;

    char* ws = (char*)d_ws;
    const size_t BUF_BYTES = (size_t)NN * D * sizeof(float);   // 51.2 MB
    float*  buf       = (float*)ws;                            // x -> hidden -> y
    double* stats     = (double*)(ws + BUF_BYTES);             // 256 doubles
    float*  sc_sh     = (float*)(ws + BUF_BYTES + 2048);       // 256 floats
    char*   p         = ws + BUF_BYTES + 4096;
    int*    cnt       = (int*)p;            p += (size_t)NN * 4;        // 400 KB
    int*    pre       = (int*)p;            p += (size_t)NN * 4;        // 400 KB
    int*    row_start = (int*)p;            p += (size_t)(NN + 4) * 4;  // 400 KB
    int*    cursor    = (int*)p;            p += (size_t)NN * 4;        // 400 KB
    int*    blkSum    = (int*)p;            p += 512;
    int*    blkOfs    = (int*)p;            p += 512;
    int*    eidx      = (int*)p;                                        // 6.4 MB

    // zero: degree counters + bn stats
    hipMemsetAsync(cnt, 0, (size_t)NN * 4, stream);
    hipMemsetAsync(stats, 0, 2048, stream);

    // ---- CSR build (counting sort by dst) ----
    count_kernel<<<(NE + 255) / 256, 256, 0, stream>>>(dst, cnt);
    scan_local_kernel<<<SCAN_NBLK, 256, 0, stream>>>(cnt, pre, blkSum);
    scan_blk_kernel<<<1, 128, 0, stream>>>(blkSum, blkOfs);
    scan_finish_kernel<<<(NN + 256) / 256, 256, 0, stream>>>(pre, blkOfs, row_start, cursor);
    fill_kernel<<<(NE + 255) / 256, 256, 0, stream>>>(src, dst, cursor, eidx);

    // ---- gather: x = (1+eps)*h + segment_sum(h[src] by dst) ----
    gather_kernel<<<NN * 32 / 256, 256, 0, stream>>>(h, row_start, eidx, eps, buf);

    // ---- MLP ----
    mlp_gemm_kernel<1><<<NN / TILE_R, 256, 0, stream>>>(buf, W1, b1, nullptr, buf);
    mlp_gemm_kernel<2><<<NN / TILE_R, 256, 0, stream>>>(buf, W2, b2, snorm, buf);

    // ---- batch norm + residual ----
    bn_stats_kernel<<<(NN + 255) / 256, 256, 0, stream>>>(buf, stats);
    bn_prep_kernel<<<1, D, 0, stream>>>(stats, gamma, beta, sc_sh);
    finalize_kernel<<<NN * D / 4 / 256, 256, 0, stream>>>(buf, h, sc_sh, out);
}

// Round 3
// 566.174 us; speedup vs baseline: 5.2672x; 1.0606x over previous
//
#include <hip/hip_runtime.h>

#define D 128
#define NN 100000
#define NE 1600000
#define SCAN_NBLK 98        // ceil(NN / 1024)
#define GT_ROWS 128
#define GEMM_NT ((NN + GT_ROWS - 1) / GT_ROWS)   // 782
#define GEMM_GRID 256

// ---------------------------------------------------------------------------
// CSR build K1: per-dst degree count (int4 loads)
// ---------------------------------------------------------------------------
__global__ __launch_bounds__(256) void count_kernel(
    const int* __restrict__ dst, int* __restrict__ cnt)
{
    int g4 = blockIdx.x * 256 + threadIdx.x;
    if (g4 >= NE / 4) return;
    int4 d = ((const int4*)dst)[g4];
    atomicAdd(&cnt[d.x], 1);
    atomicAdd(&cnt[d.y], 1);
    atomicAdd(&cnt[d.z], 1);
    atomicAdd(&cnt[d.w], 1);
}

// ---------------------------------------------------------------------------
// CSR build K2: per-block exclusive scan (1024 elements / block)
// ---------------------------------------------------------------------------
__global__ __launch_bounds__(256) void scan_local_kernel(
    const int* __restrict__ cnt, int* __restrict__ pre, int* __restrict__ blkSum)
{
    __shared__ int lds[256];
    const int t = threadIdx.x;
    const int base = blockIdx.x * 1024 + t * 4;
    int4 v = {0, 0, 0, 0};
    if (base + 3 < NN) v = *(const int4*)&cnt[base];
    else {
        if (base + 0 < NN) v.x = cnt[base + 0];
        if (base + 1 < NN) v.y = cnt[base + 1];
        if (base + 2 < NN) v.z = cnt[base + 2];
        if (base + 3 < NN) v.w = cnt[base + 3];
    }
    const int s = v.x + v.y + v.z + v.w;
    lds[t] = s;
    __syncthreads();
    for (int off = 1; off < 256; off <<= 1) {
        int val = 0;
        if (t >= off) val = lds[t - off];
        __syncthreads();
        if (t >= off) lds[t] += val;
        __syncthreads();
    }
    const int excl = lds[t] - s;
    if (t == 255) blkSum[blockIdx.x] = lds[255];
    int4 o;
    o.x = excl;
    o.y = excl + v.x;
    o.z = excl + v.x + v.y;
    o.w = excl + v.x + v.y + v.z;
    if (base + 3 < NN) *(int4*)&pre[base] = o;
    else {
        if (base + 0 < NN) pre[base + 0] = o.x;
        if (base + 1 < NN) pre[base + 1] = o.y;
        if (base + 2 < NN) pre[base + 2] = o.z;
        if (base + 3 < NN) pre[base + 3] = o.w;
    }
}

// ---------------------------------------------------------------------------
// CSR build K3: scan the 98 block sums (single block)
// ---------------------------------------------------------------------------
__global__ __launch_bounds__(128) void scan_blk_kernel(
    const int* __restrict__ blkSum, int* __restrict__ blkOfs)
{
    __shared__ int lds[128];
    const int t = threadIdx.x;
    int s = (t < SCAN_NBLK) ? blkSum[t] : 0;
    lds[t] = s;
    __syncthreads();
    for (int off = 1; off < 128; off <<= 1) {
        int val = 0;
        if (t >= off) val = lds[t - off];
        __syncthreads();
        if (t >= off) lds[t] += val;
        __syncthreads();
    }
    blkOfs[t] = lds[t] - s;
}

// ---------------------------------------------------------------------------
// CSR build K4: row_start[n] = pre[n] + blkOfs[n/1024]; cursor = copy
// ---------------------------------------------------------------------------
__global__ __launch_bounds__(256) void scan_finish_kernel(
    const int* __restrict__ pre, const int* __restrict__ blkOfs,
    int* __restrict__ row_start, int* __restrict__ cursor)
{
    int n = blockIdx.x * 256 + threadIdx.x;
    if (n > NN) return;
    int v = (n == NN) ? NE : pre[n] + blkOfs[n >> 10];
    row_start[n] = v;
    if (n < NN) cursor[n] = v;
}

// ---------------------------------------------------------------------------
// CSR build K5: bucket the src ids by dst
// ---------------------------------------------------------------------------
__global__ __launch_bounds__(256) void fill_kernel(
    const int* __restrict__ src, const int* __restrict__ dst,
    int* __restrict__ cursor, int* __restrict__ eidx)
{
    int e = blockIdx.x * 256 + threadIdx.x;
    if (e >= NE) return;
    int pos = atomicAdd(&cursor[dst[e]], 1);
    eidx[pos] = src[e];
}

// ---------------------------------------------------------------------------
// K6: gather  x[n] = (1+eps)*h[n] + sum_{e in csr(n)} h[eidx[e]]
//     32 lanes per node, float4 per lane, 2-edge unroll (2 acc chains for MLP)
// ---------------------------------------------------------------------------
__global__ __launch_bounds__(256) void gather_kernel(
    const float* __restrict__ h, const int* __restrict__ row_start,
    const int* __restrict__ eidx, const float* __restrict__ epsp,
    float* __restrict__ x)
{
    int gid  = blockIdx.x * 256 + threadIdx.x;
    int node = gid >> 5;
    int lane = gid & 31;
    if (node >= NN) return;
    const int s0 = row_start[node];
    const int s1 = row_start[node + 1];
    const float sc = 1.0f + epsp[0];
    float4 hv = ((const float4*)(h + (size_t)node * D))[lane];
    float ax = sc * hv.x, ay = sc * hv.y, az = sc * hv.z, aw = sc * hv.w;
    float bx = 0.f, by = 0.f, bz = 0.f, bw = 0.f;
    int e = s0;
    for (; e + 1 < s1; e += 2) {
        int sa = eidx[e];
        int sb = eidx[e + 1];
        float4 va = ((const float4*)(h + (size_t)sa * D))[lane];
        float4 vb = ((const float4*)(h + (size_t)sb * D))[lane];
        ax += va.x; ay += va.y; az += va.z; aw += va.w;
        bx += vb.x; by += vb.y; bz += vb.z; bw += vb.w;
    }
    if (e < s1) {
        int sa = eidx[e];
        float4 va = ((const float4*)(h + (size_t)sa * D))[lane];
        ax += va.x; ay += va.y; az += va.z; aw += va.w;
    }
    float4 o = {ax + bx, ay + by, az + bz, aw + bw};
    ((float4*)(x + (size_t)node * D))[lane] = o;
}

// ---------------------------------------------------------------------------
// K7/K8: tiled MLP GEMM, 128x128 tile, 8x8 micro-tile, W staged once/block,
// x transposed [k][row] in LDS with XOR chunk-swizzle (conflict-free reads),
// k-half double-buffered staging pipelined against compute.
// MODE 1: out = relu(x@W + b)
// MODE 2: out = (x@W + b) * snorm, + fused per-column sum/sumsq -> stats
// ---------------------------------------------------------------------------
template <int MODE>
__global__ __launch_bounds__(256, 1) void gemm_kernel(
    const float* __restrict__ xin, const float* __restrict__ W,
    const float* __restrict__ bias, const float* __restrict__ snorm,
    float* __restrict__ out, double* __restrict__ stats)
{
    __shared__ float wl[D * D];          // 64 KB  [k][col]
    __shared__ float xb[D * GT_ROWS];    // 64 KB  [k][row], swizzled chunks
    const int tid = threadIdx.x;

    // ---- stage W once (row-major copy) ----
    {
        const float4* Wv = (const float4*)W;
        float4* wv = (float4*)wl;
#pragma unroll
        for (int i = 0; i < 16; ++i) wv[tid + i * 256] = Wv[tid + i * 256];
    }

    const int cg = tid & 15;          // col group
    const int rg = tid >> 4;          // row group
    const int ca = cg * 4;            // cols ca..ca+3
    const int cb = 64 + cg * 4;       // cols cb..cb+3

    float4 bva = ((const float4*)bias)[cg];
    float4 bvb = ((const float4*)bias)[16 + cg];

    float ssum[8], ssq[8];
#pragma unroll
    for (int j = 0; j < 8; ++j) { ssum[j] = 0.f; ssq[j] = 0.f; }

    // ---- staging helpers ----
    float4 rstg[8];
    auto LOADH = [&](int t, int hk) {
        const int row0 = t * GT_ROWS;
#pragma unroll
        for (int i = 0; i < 8; ++i) {
            int idx = tid + i * 256;          // 0..2047
            int row = idx >> 4;               // 0..127
            int kc  = (idx & 15) + hk * 16;   // float4-k chunk 0..31
            int grow = row0 + row;
            rstg[i] = (grow < NN)
                ? ((const float4*)(xin + (size_t)grow * D))[kc]
                : make_float4(0.f, 0.f, 0.f, 0.f);
        }
    };
    auto WRITEH = [&](int hk) {
#pragma unroll
        for (int i = 0; i < 8; ++i) {
            int idx = tid + i * 256;
            int row = idx >> 4;
            int kc  = (idx & 15) + hk * 16;
            int c4  = (row >> 2) ^ (kc & 7);          // XOR chunk swizzle
            float v[4] = {rstg[i].x, rstg[i].y, rstg[i].z, rstg[i].w};
#pragma unroll
            for (int j = 0; j < 4; ++j)
                xb[(kc * 4 + j) * GT_ROWS + c4 * 4 + (row & 3)] = v[j];
        }
    };

    for (int t = blockIdx.x; t < GEMM_NT; t += GEMM_GRID) {
        float acc[8][8];
#pragma unroll
        for (int i = 0; i < 8; ++i)
#pragma unroll
            for (int j = 0; j < 8; ++j) acc[i][j] = 0.f;

        if (t == (int)blockIdx.x) LOADH(t, 0);   // prologue loads
        __syncthreads();                          // xb free (prev tile done)
        WRITEH(0);
        LOADH(t, 1);                              // H1 loads in flight
        __syncthreads();                          // H0 visible

        // compute halves
#pragma unroll 1
        for (int half = 0; half < 2; ++half) {
            const int k0 = half * 64;
#pragma unroll 4
            for (int kk = 0; kk < 64; ++kk) {
                const int k  = k0 + kk;
                const int sk = (k >> 2) & 7;
                float4 xa = *(const float4*)&xb[k * GT_ROWS + (((2 * rg) ^ sk) << 2)];
                float4 xc = *(const float4*)&xb[k * GT_ROWS + (((2 * rg + 1) ^ sk) << 2)];
                float4 wa = *(const float4*)&wl[k * D + ca];
                float4 wb = *(const float4*)&wl[k * D + cb];
                float xr[8] = {xa.x, xa.y, xa.z, xa.w, xc.x, xc.y, xc.z, xc.w};
                float wr[8] = {wa.x, wa.y, wa.z, wa.w, wb.x, wb.y, wb.z, wb.w};
#pragma unroll
                for (int i = 0; i < 8; ++i)
#pragma unroll
                    for (int j = 0; j < 8; ++j)
                        acc[i][j] = fmaf(xr[i], wr[j], acc[i][j]);
            }
            if (half == 0) {
                WRITEH(1);                         // stage H1 into LDS
                int tn = t + GEMM_GRID;
                if (tn < GEMM_NT) LOADH(tn, 0);    // prefetch next tile H0
                __syncthreads();                   // H1 visible
            }
        }

        // ---- epilogue ----
#pragma unroll
        for (int i = 0; i < 8; ++i) {
            int row = t * GT_ROWS + rg * 8 + i;
            if (row < NN) {
                float oa[4], ob[4];
                if (MODE == 1) {
                    oa[0] = fmaxf(acc[i][0] + bva.x, 0.f);
                    oa[1] = fmaxf(acc[i][1] + bva.y, 0.f);
                    oa[2] = fmaxf(acc[i][2] + bva.z, 0.f);
                    oa[3] = fmaxf(acc[i][3] + bva.w, 0.f);
                    ob[0] = fmaxf(acc[i][4] + bvb.x, 0.f);
                    ob[1] = fmaxf(acc[i][5] + bvb.y, 0.f);
                    ob[2] = fmaxf(acc[i][6] + bvb.z, 0.f);
                    ob[3] = fmaxf(acc[i][7] + bvb.w, 0.f);
                } else {
                    const float sn = snorm[row];
                    oa[0] = (acc[i][0] + bva.x) * sn;
                    oa[1] = (acc[i][1] + bva.y) * sn;
                    oa[2] = (acc[i][2] + bva.z) * sn;
                    oa[3] = (acc[i][3] + bva.w) * sn;
                    ob[0] = (acc[i][4] + bvb.x) * sn;
                    ob[1] = (acc[i][5] + bvb.y) * sn;
                    ob[2] = (acc[i][6] + bvb.z) * sn;
                    ob[3] = (acc[i][7] + bvb.w) * sn;
#pragma unroll
                    for (int j = 0; j < 4; ++j) {
                        ssum[j]     += oa[j];  ssq[j]     += oa[j] * oa[j];
                        ssum[4 + j] += ob[j];  ssq[4 + j] += ob[j] * ob[j];
                    }
                }
                float* op = out + (size_t)row * D;
                *(float4*)&op[ca] = *(float4*)&oa[0];
                *(float4*)&op[cb] = *(float4*)&ob[0];
            }
        }
    }

    // ---- fused BN stats reduce (MODE 2): reuse xb as scratch ----
    if (MODE == 2) {
        float* red = xb;   // 16 x 128 floats needed, xb has 16384
        __syncthreads();
#pragma unroll
        for (int j = 0; j < 4; ++j) {
            red[rg * D + ca + j] = ssum[j];
            red[rg * D + cb + j] = ssum[4 + j];
        }
        __syncthreads();
        if (tid < D) {
            float s = 0.f;
#pragma unroll
            for (int r = 0; r < 16; ++r) s += red[r * D + tid];
            atomicAdd(&stats[tid], (double)s);
        }
        __syncthreads();
#pragma unroll
        for (int j = 0; j < 4; ++j) {
            red[rg * D + ca + j] = ssq[j];
            red[rg * D + cb + j] = ssq[4 + j];
        }
        __syncthreads();
        if (tid < D) {
            float s = 0.f;
#pragma unroll
            for (int r = 0; r < 16; ++r) s += red[r * D + tid];
            atomicAdd(&stats[D + tid], (double)s);
        }
    }
}

// ---------------------------------------------------------------------------
// K9: fold stats into per-column scale/shift
// ---------------------------------------------------------------------------
__global__ void bn_prep_kernel(const double* __restrict__ stats,
                               const float* __restrict__ gamma,
                               const float* __restrict__ beta,
                               float* __restrict__ sc_sh)
{
    int c = threadIdx.x;
    double mean = stats[c] * (1.0 / NN);
    double var  = stats[D + c] * (1.0 / NN) - mean * mean;
    float rs = rsqrtf((float)var + 1e-5f);
    float sc = gamma[c] * rs;
    sc_sh[c]     = sc;
    sc_sh[D + c] = beta[c] - (float)mean * sc;
}

// ---------------------------------------------------------------------------
// K10: out = h + relu(y*sc + sh)
// ---------------------------------------------------------------------------
__global__ __launch_bounds__(256) void finalize_kernel(
    const float* __restrict__ y, const float* __restrict__ h,
    const float* __restrict__ sc_sh, float* __restrict__ out)
{
    int i  = blockIdx.x * 256 + threadIdx.x;
    int cf = i & 31;
    float4 yv = ((const float4*)y)[i];
    float4 hv = ((const float4*)h)[i];
    float4 sc = ((const float4*)sc_sh)[cf];
    float4 sh = ((const float4*)(sc_sh + D))[cf];
    float4 o;
    o.x = hv.x + fmaxf(fmaf(yv.x, sc.x, sh.x), 0.0f);
    o.y = hv.y + fmaxf(fmaf(yv.y, sc.y, sh.y), 0.0f);
    o.z = hv.z + fmaxf(fmaf(yv.z, sc.z, sh.z), 0.0f);
    o.w = hv.w + fmaxf(fmaf(yv.w, sc.w, sh.w), 0.0f);
    ((float4*)out)[i] = o;
}

// ---------------------------------------------------------------------------
extern "C" void kernel_launch(void* const* d_in, const int* in_sizes, int n_in,
                              void* d_out, int out_size, void* d_ws, size_t ws_size,
                              hipStream_t stream)
{
    const float* h     = (const float*)d_in[0];
    const float* snorm = (const float*)d_in[1];
    const float* eps   = (const float*)d_in[2];
    const float* W1    = (const float*)d_in[3];
    const float* b1    = (const float*)d_in[4];
    const float* W2    = (const float*)d_in[5];
    const float* b2    = (const float*)d_in[6];
    const float* gamma = (const float*)d_in[7];
    const float* beta  = (const float*)d_in[8];
    const int*   src   = (const int*)d_in[9];
    const int*   dst   = (const int*)d_in[10];
    float* out = (float*)d_out;

    char* ws = (char*)d_ws;
    const size_t BUF_BYTES = (size_t)NN * D * sizeof(float);   // 51.2 MB
    float*  buf       = (float*)ws;                            // x -> hidden -> y
    double* stats     = (double*)(ws + BUF_BYTES);             // 256 doubles
    float*  sc_sh     = (float*)(ws + BUF_BYTES + 2048);       // 256 floats
    char*   p         = ws + BUF_BYTES + 4096;
    int*    cnt       = (int*)p;            p += (size_t)NN * 4;
    int*    pre       = (int*)p;            p += (size_t)NN * 4;
    int*    row_start = (int*)p;            p += (size_t)(NN + 4) * 4;
    int*    cursor    = (int*)p;            p += (size_t)NN * 4;
    int*    blkSum    = (int*)p;            p += 512;
    int*    blkOfs    = (int*)p;            p += 512;
    int*    eidx      = (int*)p;                               // 6.4 MB

    hipMemsetAsync(cnt, 0, (size_t)NN * 4, stream);
    hipMemsetAsync(stats, 0, 2048, stream);

    // ---- CSR build (counting sort by dst) ----
    count_kernel<<<(NE / 4 + 255) / 256, 256, 0, stream>>>(dst, cnt);
    scan_local_kernel<<<SCAN_NBLK, 256, 0, stream>>>(cnt, pre, blkSum);
    scan_blk_kernel<<<1, 128, 0, stream>>>(blkSum, blkOfs);
    scan_finish_kernel<<<(NN + 256) / 256 + 1, 256, 0, stream>>>(pre, blkOfs, row_start, cursor);
    fill_kernel<<<(NE + 255) / 256, 256, 0, stream>>>(src, dst, cursor, eidx);

    // ---- gather: x = (1+eps)*h + segment_sum(h[src] by dst) ----
    gather_kernel<<<NN * 32 / 256, 256, 0, stream>>>(h, row_start, eidx, eps, buf);

    // ---- MLP (in-place on buf), BN stats fused into GEMM2 ----
    gemm_kernel<1><<<GEMM_GRID, 256, 0, stream>>>(buf, W1, b1, nullptr, buf, nullptr);
    gemm_kernel<2><<<GEMM_GRID, 256, 0, stream>>>(buf, W2, b2, snorm, buf, stats);

    // ---- batch norm fold + residual ----
    bn_prep_kernel<<<1, D, 0, stream>>>(stats, gamma, beta, sc_sh);
    finalize_kernel<<<NN * D / 4 / 256, 256, 0, stream>>>(buf, h, sc_sh, out);
}